// Round 1
// baseline (249.255 us; speedup 1.0000x reference)
//
#include <hip/hip_runtime.h>
#include <hip/hip_bf16.h>

typedef unsigned short us;
typedef __attribute__((ext_vector_type(8))) __bf16 bf16x8;
typedef __attribute__((ext_vector_type(4))) float f32x4;

#define MFMA16(a, b, c) __builtin_amdgcn_mfma_f32_16x16x32_bf16(a, b, c, 0, 0, 0)
#define FENCE asm volatile("" ::: "memory")

static __device__ __forceinline__ us f2bf(float f) {
  __hip_bfloat16 h = __float2bfloat16(f);
  return __builtin_bit_cast(us, h);
}

// async global->LDS, 16B per lane; LDS dest is wave-uniform base + lane*16
static __device__ __forceinline__ void gll16(const us* g, us* l) {
  __builtin_amdgcn_global_load_lds((const __attribute__((address_space(1))) void*)g,
                                   (__attribute__((address_space(3))) void*)l,
                                   16, 0, 0);
}

// ------------------------------------------------ prep: casts + rope table --
__global__ void prep_kernel(const float* __restrict__ x, const float* __restrict__ wq,
                            const float* __restrict__ wo, us* __restrict__ xb,
                            us* __restrict__ wqb, us* __restrict__ wob,
                            float* __restrict__ ct, float* __restrict__ st) {
  const int blk = blockIdx.x;
  const int tid = threadIdx.x;
  if (blk < 12288) {
    const float* in;
    us* out;
    int i;
    if (blk < 8192)      { in = x;  out = xb;  i = blk * 256 + tid; }
    else if (blk < 11264){ in = wq; out = wqb; i = (blk - 8192) * 256 + tid; }
    else                 { in = wo; out = wob; i = (blk - 11264) * 256 + tid; }
    float4 v = ((const float4*)in)[i];
    ushort4 o;
    o.x = f2bf(v.x); o.y = f2bf(v.y); o.z = f2bf(v.z); o.w = f2bf(v.w);
    ((ushort4*)out)[i] = o;
  } else {
    int i = (blk - 12288) * 256 + tid;
    int t = i >> 6, d = i & 63;
    float ang = (float)t * exp2f((float)d * -0.20762050593046014f);
    float s, c;
    sincosf(ang, &s, &c);
    ct[i] = c;
    st[i] = s;
  }
}

// ------------------------------------------- GEMM1: qkv + RoPE + scatter ----
// 256x256 tile, BK=64, 512 thr (8 waves: 2M x 4N), 8-phase-per-2-K-tiles
// schedule (T3+T4+T5): 4 phases per K-tile, counted vmcnt(6) once per K-tile
// (never 0 in steady state), setprio(1) around each 16-MFMA quadrant.
// LDS 128 KiB = 2dbuf x (A[256][64] + B[256][64]) bf16, xor-swizzled slots.
//
// Wave col map keeps RoPE pairs lane-local: col = (wc>>1)*128 + (wc&1)*32 +
// (nt&1)*16 + (nt>>1)*64 + l15  ->  d^64 partner is acc[mt][nt^2] same lane.
//
// Half-tiles per K-tile t (buf t&1): h0=A rows0-127, h1=A rows128-255,
// h2=B rows0-127, h3=B rows128-255. Reads: A-M0@p1, A-M1@p2, B-N0@p1,
// B-N1@p3 -> A halves retire after p2, B halves after p3 (phase-end barrier).
// Staging: p1->(t+1).h3, p3->(t+2).h0, p4->(t+2).h1+h2  (each target's old
// content retired >=1 barrier earlier). vmcnt(6)@p4 leaves exactly the 3
// newest half-tiles ((t+2).h0,h1,h2) in flight and guarantees t+1 resident.
__global__ __launch_bounds__(512, 2)
void qkv_rope_kernel(const us* __restrict__ A, const us* __restrict__ B,
                     const float* __restrict__ ctab, const float* __restrict__ stab,
                     us* __restrict__ qb, us* __restrict__ kb, us* __restrict__ vtb) {
  __shared__ __align__(16) us smem[65536]; // 128 KB
  us* sAb = smem;          // [2][256*64]
  us* sBb = smem + 32768;  // [2][256*64]

  const int tid = threadIdx.x;
  const int lane = tid & 63;
  const int wave = tid >> 6;
  const int l15 = lane & 15;
  const int lq = lane >> 4;
  const int wr = wave >> 2; // 0..1 (M)
  const int wc = wave & 3;  // 0..3 (N)
  const int m0 = blockIdx.x * 256;
  const int n0 = blockIdx.y * 256;

  // stage one 8KB chunk (j=0/1) of a 128x64 half-tile; linear LDS dest,
  // pre-swizzled global source (slot sb = s ^ (row&7))
  auto stage = [&](const us* gbase, us* lds, int j) {
    int P = j * 512 + tid;
    int row = P >> 3;
    int sb = (P & 7) ^ (row & 7);
    gll16(gbase + (size_t)row * 1024 + sb * 8, lds + (j * 512 + wave * 64) * 8);
  };
  auto stage_half = [&](int t, int h) {
    int c = t & 1;
    const us* g;
    us* l;
    if (h < 2) { g = A + (size_t)(m0 + h * 128) * 1024 + t * 64; l = sAb + c * 16384 + h * 8192; }
    else       { g = B + (size_t)(n0 + (h - 2) * 128) * 1024 + t * 64; l = sBb + c * 16384 + (h - 2) * 8192; }
    stage(g, l, 0);
    stage(g, l, 1);
  };
  auto nrow = [&](int nt) {
    return (wc >> 1) * 128 + (wc & 1) * 32 + (nt & 1) * 16 + (nt >> 1) * 64 + l15;
  };

  f32x4 acc[8][4] = {};
  bf16x8 a0[4][2], a1[4][2], b0[2][2], b1[2][2];

  // prologue: k0 fully + k1.h0-h2 in flight; vmcnt(6) -> k0 resident
#pragma unroll
  for (int h = 0; h < 4; ++h) stage_half(0, h);
  stage_half(1, 0); stage_half(1, 1); stage_half(1, 2);
  asm volatile("s_waitcnt vmcnt(6)" ::: "memory");
  FENCE; __builtin_amdgcn_s_barrier(); FENCE;

  for (int kt = 0; kt < 16; ++kt) {
    const int c = kt & 1;
    const us* sAc = sAb + c * 16384;
    const us* sBc = sBb + c * 16384;

    // ---- phase 1: read A-M0(8)+B-N0(4); stage (kt+1).h3; MFMA M0xN0 ----
#pragma unroll
    for (int mt = 0; mt < 4; ++mt)
#pragma unroll
      for (int kk = 0; kk < 2; ++kk) {
        int m = wr * 128 + mt * 16 + l15;
        a0[mt][kk] = *(const bf16x8*)(sAc + m * 64 + (((kk * 4 + lq) ^ (m & 7)) * 8));
      }
#pragma unroll
    for (int nt = 0; nt < 2; ++nt)
#pragma unroll
      for (int kk = 0; kk < 2; ++kk) {
        int n = nrow(nt);
        b0[nt][kk] = *(const bf16x8*)(sBc + n * 64 + (((kk * 4 + lq) ^ (n & 7)) * 8));
      }
    if (kt < 15) stage_half(kt + 1, 3);
    FENCE; __builtin_amdgcn_s_barrier(); FENCE;
    asm volatile("s_waitcnt lgkmcnt(0)" ::: "memory");
    __builtin_amdgcn_sched_barrier(0);
    __builtin_amdgcn_s_setprio(1);
#pragma unroll
    for (int mt = 0; mt < 4; ++mt)
#pragma unroll
      for (int nt = 0; nt < 2; ++nt)
#pragma unroll
        for (int kk = 0; kk < 2; ++kk)
          acc[mt][nt] = MFMA16(a0[mt][kk], b0[nt][kk], acc[mt][nt]);
    __builtin_amdgcn_s_setprio(0);
    FENCE; __builtin_amdgcn_s_barrier(); FENCE;

    // ---- phase 2: read A-M1(8); MFMA M1xN0 ----
#pragma unroll
    for (int mt = 0; mt < 4; ++mt)
#pragma unroll
      for (int kk = 0; kk < 2; ++kk) {
        int m = wr * 128 + 64 + mt * 16 + l15;
        a1[mt][kk] = *(const bf16x8*)(sAc + m * 64 + (((kk * 4 + lq) ^ (m & 7)) * 8));
      }
    FENCE; __builtin_amdgcn_s_barrier(); FENCE;
    asm volatile("s_waitcnt lgkmcnt(0)" ::: "memory");
    __builtin_amdgcn_sched_barrier(0);
    __builtin_amdgcn_s_setprio(1);
#pragma unroll
    for (int mt = 0; mt < 4; ++mt)
#pragma unroll
      for (int nt = 0; nt < 2; ++nt)
#pragma unroll
        for (int kk = 0; kk < 2; ++kk)
          acc[4 + mt][nt] = MFMA16(a1[mt][kk], b0[nt][kk], acc[4 + mt][nt]);
    __builtin_amdgcn_s_setprio(0);
    FENCE; __builtin_amdgcn_s_barrier(); FENCE;

    // ---- phase 3: read B-N1(4); stage (kt+2).h0; MFMA M1xN1 ----
#pragma unroll
    for (int nt = 0; nt < 2; ++nt)
#pragma unroll
      for (int kk = 0; kk < 2; ++kk) {
        int n = nrow(2 + nt);
        b1[nt][kk] = *(const bf16x8*)(sBc + n * 64 + (((kk * 4 + lq) ^ (n & 7)) * 8));
      }
    if (kt < 14) stage_half(kt + 2, 0);
    FENCE; __builtin_amdgcn_s_barrier(); FENCE;
    asm volatile("s_waitcnt lgkmcnt(0)" ::: "memory");
    __builtin_amdgcn_sched_barrier(0);
    __builtin_amdgcn_s_setprio(1);
#pragma unroll
    for (int mt = 0; mt < 4; ++mt)
#pragma unroll
      for (int nt = 0; nt < 2; ++nt)
#pragma unroll
        for (int kk = 0; kk < 2; ++kk)
          acc[4 + mt][2 + nt] = MFMA16(a1[mt][kk], b1[nt][kk], acc[4 + mt][2 + nt]);
    __builtin_amdgcn_s_setprio(0);
    FENCE; __builtin_amdgcn_s_barrier(); FENCE;

    // ---- phase 4: stage (kt+2).h1+h2; MFMA M0xN1; vmcnt(6); barrier ----
    if (kt < 14) { stage_half(kt + 2, 1); stage_half(kt + 2, 2); }
    FENCE; __builtin_amdgcn_s_barrier(); FENCE;
    __builtin_amdgcn_s_setprio(1);
#pragma unroll
    for (int mt = 0; mt < 4; ++mt)
#pragma unroll
      for (int nt = 0; nt < 2; ++nt)
#pragma unroll
        for (int kk = 0; kk < 2; ++kk)
          acc[mt][2 + nt] = MFMA16(a0[mt][kk], b1[nt][kk], acc[mt][2 + nt]);
    __builtin_amdgcn_s_setprio(0);
    if (kt < 14) { asm volatile("s_waitcnt vmcnt(6)" ::: "memory"); }
    else         { asm volatile("s_waitcnt vmcnt(0)" ::: "memory"); }
    FENCE; __builtin_amdgcn_s_barrier(); FENCE;
  }

  // ---- epilogue: RoPE (q/k) or transpose (v), via LDS, per head group ----
  const int b = m0 >> 12;
  const int tg0 = m0 & 4095;
  const int g0 = blockIdx.y * 2;
  const int which = g0 >> 3;
  us* sE = smem;

  if (which < 2) {
    us* outp = (which == 0) ? qb : kb;
    for (int ch = 0; ch < 2; ++ch) {
      const int h = (g0 + ch) & 7;
      if ((wc >> 1) == ch) {
        const int dl0 = (wc & 1) * 32 + l15;
#pragma unroll
        for (int mt = 0; mt < 8; ++mt)
#pragma unroll
          for (int r = 0; r < 4; ++r) {
            const int row = wr * 128 + mt * 16 + lq * 4 + r;
            const int tg = tg0 + row;
            const float c0 = ctab[tg * 64 + dl0], c1 = ctab[tg * 64 + dl0 + 16];
            const float s0 = stab[tg * 64 + dl0], s1 = stab[tg * 64 + dl0 + 16];
#pragma unroll
            for (int nt = 0; nt < 4; ++nt) {
              float xv = acc[mt][nt][r];
              float xp = acc[mt][nt ^ 2][r];
              float rot = (nt < 2) ? -xp : xp;
              float y = xv * ((nt & 1) ? c1 : c0) + rot * ((nt & 1) ? s1 : s0);
              sE[row * 136 + (wc & 1) * 32 + (nt & 1) * 16 + (nt >> 1) * 64 + l15] = f2bf(y);
            }
          }
      }
      __syncthreads();
      const size_t obase = ((size_t)(b * 8 + h) * 4096 + tg0) * 128;
      for (int it = 0; it < 8; ++it) {
        int idx = it * 512 + tid;
        int row = idx >> 4;
        int col = (idx & 15) * 8;
        *(uint4*)(outp + obase + (size_t)row * 128 + col) = *(const uint4*)(sE + row * 136 + col);
      }
      __syncthreads();
    }
  } else {
    // V: write transposed-at-store bf16 tile [d 128][t 256+pad], row-copy out
    for (int ch = 0; ch < 2; ++ch) {
      const int h = (g0 + ch) & 7;
      if ((wc >> 1) == ch) {
#pragma unroll
        for (int mt = 0; mt < 8; ++mt)
#pragma unroll
          for (int nt = 0; nt < 4; ++nt) {
            const int dl = (wc & 1) * 32 + (nt & 1) * 16 + (nt >> 1) * 64 + l15;
#pragma unroll
            for (int r = 0; r < 4; ++r) {
              const int row = wr * 128 + mt * 16 + lq * 4 + r;
              sE[dl * 264 + row] = f2bf(acc[mt][nt][r]);
            }
          }
      }
      __syncthreads();
      const size_t obase = (size_t)(b * 8 + h) * 128 * 4096 + tg0;
      for (int it = 0; it < 8; ++it) {
        int idx = it * 512 + tid;
        int d = idx >> 5;
        int tl = (idx & 31) * 8;
        *(uint4*)(vtb + obase + (size_t)d * 4096 + tl) = *(const uint4*)(sE + d * 264 + tl);
      }
      __syncthreads();
    }
  }
}

// --------------------------------------------------- flash attention --------
// (unchanged this round)
template <int MASK>
__device__ __forceinline__ void p_write(f32x4 (&s)[2][4], us* __restrict__ sP,
                                        int t0, int tj0, int wm2, int lq, int l15) {
  const float C2 = 0.08838834764831845f * 1.4426950408889634f; // scale * log2(e)
#pragma unroll
  for (int mt = 0; mt < 2; ++mt)
#pragma unroll
    for (int nt = 0; nt < 4; ++nt) {
      const int jg = tj0 + nt * 16 + l15;
      const int cb = (nt * 16 + l15) >> 3;
      const int co = l15 & 7;
#pragma unroll
      for (int r = 0; r < 4; ++r) {
        const int rowl = wm2 + mt * 16 + lq * 4 + r;
        float v = s[mt][nt][r];
        if (MASK == 1) v = (jg + 512 >= t0 + rowl) ? v : -3.0e38f;
        if (MASK == 2) v = (jg <= t0 + rowl) ? v : -3.0e38f;
        sP[rowl * 64 + ((cb ^ (rowl & 7)) * 8) + co] = f2bf(exp2f(v * C2));
      }
    }
}

__global__ __launch_bounds__(256, 2)
void flash_kernel(const us* __restrict__ qg, const us* __restrict__ kg,
                  const us* __restrict__ vg, us* __restrict__ ao) {
  __shared__ us smem[40960];
  us* sK = smem;
  us* sV = smem + 16384;
  us* sP = smem + 32768;

  const int tid = threadIdx.x;
  const int lane = tid & 63;
  const int wave = tid >> 6;
  const int l15 = lane & 15;
  const int lq = lane >> 4;
  const int qx = blockIdx.x;
  const int h = blockIdx.y;
  const int b = blockIdx.z;
  const int t0 = qx * 128;
  const size_t bh = (size_t)(b * 8 + h);
  const int wm2 = wave * 32;

  bf16x8 qf[2][4];
#pragma unroll
  for (int mt = 0; mt < 2; ++mt)
#pragma unroll
    for (int ks = 0; ks < 4; ++ks)
      qf[mt][ks] = *(const bf16x8*)(qg + (bh * 4096 + t0 + wm2 + mt * 16 + l15) * 128 +
                                    ks * 32 + lq * 8);

  union { us u[8]; bf16x8 v; } one_u;
#pragma unroll
  for (int i = 0; i < 8; ++i) one_u.u[i] = 0x3F80;
  const bf16x8 vone = one_u.v;

  f32x4 o[2][9] = {};

  const int lo = t0 - 512;
  const int jtmin = (lo <= 0) ? 0 : (lo >> 6);
  const int jtmax = (t0 + 127) >> 6;
  const bool wmask = (t0 >= 512);

  auto stage = [&](int jt, int buf) {
    const int tj0 = jt * 64;
    us* dK = sK + buf * 8192;
    us* dV = sV + buf * 8192;
    for (int i = 0; i < 4; ++i) {
      int c = wave * 4 + i;
      int P = c * 64 + lane;
      int rowK = P >> 4;
      int cbK = (P & 15) ^ (rowK & 15);
      gll16(kg + (bh * 4096 + tj0 + rowK) * 128 + cbK * 8, dK + c * 512);
      int rowV = P >> 3;
      int cbV = (P & 7) ^ (rowV & 7);
      gll16(vg + (bh * 128 + rowV) * 4096 + tj0 + cbV * 8, dV + c * 512);
    }
  };

  stage(jtmin, 0);
  int cur = 0;

  for (int jt = jtmin; jt <= jtmax; ++jt) {
    __syncthreads();
    if (jt < jtmax) stage(jt + 1, cur ^ 1);

    const int tj0 = jt * 64;
    const us* sKc = sK + cur * 8192;
    const us* sVc = sV + cur * 8192;

    f32x4 s[2][4] = {};
#pragma unroll
    for (int ks = 0; ks < 4; ++ks) {
      const int cbr = ks * 4 + lq;
#pragma unroll
      for (int nt = 0; nt < 4; ++nt) {
        int n = nt * 16 + l15;
        bf16x8 bk = *(const bf16x8*)(sKc + (n * 16 + (cbr ^ (n & 15))) * 8);
#pragma unroll
        for (int mt = 0; mt < 2; ++mt)
          s[mt][nt] = MFMA16(qf[mt][ks], bk, s[mt][nt]);
      }
    }

    if (jt >= jtmax - 1)               p_write<2>(s, sP, t0, tj0, wm2, lq, l15);
    else if (wmask && jt <= jtmin + 1) p_write<1>(s, sP, t0, tj0, wm2, lq, l15);
    else                               p_write<0>(s, sP, t0, tj0, wm2, lq, l15);

#pragma unroll
    for (int ks = 0; ks < 2; ++ks) {
#pragma unroll
      for (int mt = 0; mt < 2; ++mt) {
        bf16x8 ap = *(const bf16x8*)(sP + (wm2 + mt * 16 + l15) * 64 +
                                     (((ks * 4 + lq) ^ (l15 & 7)) * 8));
#pragma unroll
        for (int dt = 0; dt < 8; ++dt) {
          int dd = dt * 16 + l15;
          bf16x8 bv = *(const bf16x8*)(sVc + (dd * 8 + ((ks * 4 + lq) ^ (dd & 7))) * 8);
          o[mt][dt] = MFMA16(ap, bv, o[mt][dt]);
        }
        o[mt][8] = MFMA16(ap, vone, o[mt][8]);
      }
    }
    cur ^= 1;
  }

#pragma unroll
  for (int mt = 0; mt < 2; ++mt)
#pragma unroll
    for (int r = 0; r < 4; ++r) {
      const float inv = 1.0f / o[mt][8][r];
      const int rowl = wm2 + mt * 16 + lq * 4 + r;
      const size_t base = ((size_t)b * 4096 + t0 + rowl) * 1024 + h * 128;
#pragma unroll
      for (int dt = 0; dt < 8; ++dt)
        ao[base + dt * 16 + l15] = f2bf(o[mt][dt][r] * inv);
    }
}

// ------------------------------------------------ GEMM3: out = ao @ w_o^T ---
__global__ __launch_bounds__(256, 2)
void out_proj_kernel(const us* __restrict__ A, const us* __restrict__ B, float* __restrict__ C) {
  __shared__ us sA[128 * 64];
  __shared__ us sB[128 * 64];
  const int tid = threadIdx.x;
  const int lane = tid & 63;
  const int wave = tid >> 6;
  const int l15 = lane & 15;
  const int lq = lane >> 4;
  const int m0 = blockIdx.x * 128;
  const int n0 = blockIdx.y * 128;
  const int wm = (wave & 1) * 64;
  const int wn = (wave >> 1) * 64;
  f32x4 acc[4][4] = {};
  for (int k0 = 0; k0 < 1024; k0 += 64) {
    for (int i = 0; i < 4; ++i) {
      int c = wave * 4 + i;
      int P = c * 64 + lane;
      int row = P >> 3;
      int cb = (P & 7) ^ (row & 7);
      gll16(A + (size_t)(m0 + row) * 1024 + k0 + cb * 8, sA + c * 512);
      gll16(B + (size_t)(n0 + row) * 1024 + k0 + cb * 8, sB + c * 512);
    }
    __syncthreads();
#pragma unroll
    for (int kk = 0; kk < 64; kk += 32) {
      const int cbr = (kk + lq * 8) >> 3;
      bf16x8 av[4], bv[4];
#pragma unroll
      for (int mt = 0; mt < 4; ++mt) {
        int m = wm + mt * 16 + l15;
        av[mt] = *(const bf16x8*)(sA + (m * 8 + (cbr ^ (m & 7))) * 8);
      }
#pragma unroll
      for (int nt = 0; nt < 4; ++nt) {
        int n = wn + nt * 16 + l15;
        bv[nt] = *(const bf16x8*)(sB + (n * 8 + (cbr ^ (n & 7))) * 8);
      }
#pragma unroll
      for (int mt = 0; mt < 4; ++mt)
#pragma unroll
        for (int nt = 0; nt < 4; ++nt)
          acc[mt][nt] = MFMA16(av[mt], bv[nt], acc[mt][nt]);
    }
    __syncthreads();
  }
#pragma unroll
  for (int mt = 0; mt < 4; ++mt)
#pragma unroll
    for (int nt = 0; nt < 4; ++nt)
#pragma unroll
      for (int r = 0; r < 4; ++r)
        C[(size_t)(m0 + wm + mt * 16 + lq * 4 + r) * 1024 + (n0 + wn + nt * 16 + l15)] =
            acc[mt][nt][r];
}

// ---------------------------------------------------------------- launch ----
extern "C" void kernel_launch(void* const* d_in, const int* in_sizes, int n_in,
                              void* d_out, int out_size, void* d_ws, size_t ws_size,
                              hipStream_t stream) {
  const float* x     = (const float*)d_in[0];  // [2,4096,1024]
  const float* w_qkv = (const float*)d_in[1];  // [3072,1024]
  const float* w_o   = (const float*)d_in[2];  // [1024,1024]
  float* out = (float*)d_out;                  // [2,4096,1024] fp32

  us* xb  = (us*)d_ws;                          // 8192*1024
  us* wqb = xb  + (size_t)8192 * 1024;          // 3072*1024
  us* wob = wqb + (size_t)3072 * 1024;          // 1024*1024
  us* qb  = wob + (size_t)1024 * 1024;          // [2][8][4096][128]
  us* kb  = qb  + (size_t)2 * 8 * 4096 * 128;
  us* vtb = kb  + (size_t)2 * 8 * 4096 * 128;   // [2][8][128][4096]
  us* aob = vtb + (size_t)2 * 8 * 4096 * 128;   // 8192*1024
  float* ctab = (float*)(aob + (size_t)8192 * 1024); // [4096][64]
  float* stab = ctab + (size_t)4096 * 64;

  prep_kernel<<<13312, 256, 0, stream>>>(x, w_qkv, w_o, xb, wqb, wob, ctab, stab);
  qkv_rope_kernel<<<dim3(32, 12), 512, 0, stream>>>(xb, wqb, ctab, stab, qb, kb, vtb);
  flash_kernel<<<dim3(32, 8, 2), 256, 0, stream>>>(qb, kb, vtb, aob);
  out_proj_kernel<<<dim3(64, 8), 256, 0, stream>>>(aob, wob, out);
}